// Round 1
// baseline (499.971 us; speedup 1.0000x reference)
//
#include <hip/hip_runtime.h>

// SphericalConvMHF — round 3: split-bf16 MFMA for all four GEMM stages.
// Pipeline: K0 tables(hi/lo bf16) -> K1 fwd-DFT (MFMA, x cvt in-kernel)
//   -> K2 fwd-Legendre (MFMA) -> K3 channel-mix (fp32, unchanged)
//   -> K4 inv-Legendre (MFMA, outb transpose+cvt) -> K5 inv-DFT (MFMA, XM transpose+cvt).
// Split: v = hi + lo (bf16 RTN); C = Ah*Bh + Ah*Bl + Al*Bh (drop lo*lo, ~2^-18 rel).
// XH computed in 2 batch-halves so workspace = 168,296,448 B (same as R2).
// Poison safety: unwritten outb planes (m>l chunks) are finite and multiply PT==0.
//
// R4 note: identical resubmission of the harness-verified 498.7 µs kernel —
// previous bench failed on container acquisition (infra), no counters captured.

typedef __attribute__((ext_vector_type(8))) short short8;
typedef __attribute__((ext_vector_type(4))) float f32x4;

__device__ __forceinline__ ushort bf16_rtn(float v) {
  uint u = __float_as_uint(v);
  return (ushort)((u + 0x7FFFu + ((u >> 16) & 1u)) >> 16);
}
__device__ __forceinline__ void split2(float v, ushort& h, ushort& l) {
  h = bf16_rtn(v);
  float hf = __uint_as_float(((uint)h) << 16);
  l = bf16_rtn(v - hf);
}

// ---------------- K0: table generation (fp64 recurrence, split bf16 out) ----
__global__ __launch_bounds__(256) void k_tables(
    ushort* __restrict__ Th, ushort* __restrict__ Tl,
    ushort* __restrict__ TiTh, ushort* __restrict__ TiTl,
    ushort* __restrict__ PWh, ushort* __restrict__ PWl,
    ushort* __restrict__ PTh, ushort* __restrict__ PTl) {
  const double PI = 3.14159265358979323846264338327950288;
  const int t = threadIdx.x;
  const int m = blockIdx.x;
  if (m == 128) {             // trig tables: T[mc][n] and TiT[n][mc]
    const int n = t;
    const double scale = 2.0 * PI / 256.0;
    for (int mm = 0; mm < 128; ++mm) {
      const int r = (mm * n) & 255;
      const double ang = scale * (double)r;
      const double c = cos(ang), s = sin(ang);
      const double wm = (mm == 0) ? 1.0 : 2.0;
      ushort h, l;
      split2((float)(scale * c), h, l);  Th[(2*mm)*256+n]=h;   Tl[(2*mm)*256+n]=l;
      split2((float)(-scale * s), h, l); Th[(2*mm+1)*256+n]=h; Tl[(2*mm+1)*256+n]=l;
      split2((float)(wm * c), h, l);     TiTh[n*256+2*mm]=h;   TiTl[n*256+2*mm]=l;
      split2((float)(-wm * s), h, l);    TiTh[n*256+2*mm+1]=h; TiTl[n*256+2*mm+1]=l;
    }
    return;
  }
  const int k = t;  // latitude index
  const double tj = PI * (double)k / 255.0;
  double ssum = 0.0;
  for (int kk = 1; kk <= 127; ++kk)
    ssum += 2.0 / (4.0 * (double)kk * kk - 1.0) * cos(2.0 * tj * (double)kk);
  const double cj = (k == 0 || k == 255) ? 1.0 : 2.0;
  const double wq = cj / 255.0 * (1.0 - ssum);
  const double ct = cos(tj), st = sin(tj);
  double pmm = 1.0 / sqrt(4.0 * PI);
  for (int mm = 1; mm <= m; ++mm)
    pmm = pmm * (-sqrt((2.0 * mm + 1.0) / (2.0 * mm)) * st);
  const size_t pwB = (size_t)m * 32768;                 // [l][k], k = t
  const size_t ptB = (size_t)m * 32768 + (size_t)k * 128; // [k][l]
  ushort h, l2;
  for (int l = 0; l < m; ++l) {
    PWh[pwB + l*256 + k] = 0; PWl[pwB + l*256 + k] = 0;
    PTh[ptB + l] = 0;         PTl[ptB + l] = 0;
  }
  split2((float)pmm, h, l2);        PTh[ptB + m] = h; PTl[ptB + m] = l2;
  split2((float)(pmm*wq), h, l2);   PWh[pwB + m*256 + k] = h; PWl[pwB + m*256 + k] = l2;
  if (m + 1 < 128) {
    double pl2v = pmm;
    double pl1 = sqrt(2.0 * m + 3.0) * ct * pmm;
    split2((float)pl1, h, l2);      PTh[ptB + m+1] = h; PTl[ptB + m+1] = l2;
    split2((float)(pl1*wq), h, l2); PWh[pwB + (m+1)*256 + k] = h; PWl[pwB + (m+1)*256 + k] = l2;
    for (int l = m + 2; l < 128; ++l) {
      const double dl = (double)l, dm = (double)m;
      const double a = sqrt((4.0*dl*dl - 1.0) / (dl*dl - dm*dm));
      const double b = sqrt(((dl-1.0)*(dl-1.0) - dm*dm) / (4.0*(dl-1.0)*(dl-1.0) - 1.0));
      const double pl = a * (ct * pl1 - b * pl2v);
      split2((float)pl, h, l2);      PTh[ptB + l] = h; PTl[ptB + l] = l2;
      split2((float)(pl*wq), h, l2); PWh[pwB + l*256 + k] = h; PWl[pwB + l*256 + k] = l2;
      pl2v = pl1; pl1 = pl;
    }
  }
}

// ---------------- split-bf16 MFMA GEMM ----------------
// C[i][j] = sum_k A[i][k]*B[j][k]. Block 128x128, 4 waves (64x64 each), BK=32.
// AM: 0 = A from pre-split bf16 [i][k]; 2 = A from fp32 [k][i] (transpose+cvt).
// BM: 0 = B from pre-split bf16 [j][k]; 1 = B from fp32 [j][k] (cvt).
// LDS pitch 40 shorts (80 B): 16B-aligned rows, ~2-way bank aliasing (free).
template<int AM, int BM>
__global__ __launch_bounds__(256) void mfma_gemm(
    const ushort* __restrict__ Ah, const ushort* __restrict__ Al, const float* __restrict__ Af,
    const ushort* __restrict__ Bh, const ushort* __restrict__ Bl, const float* __restrict__ Bf,
    float* __restrict__ C,
    int lda, int ldb, int ldc, int K,
    long aZ, int aShift, long bZ, int bShift, long cZ, int cColOff, int kFromZ)
{
  __shared__ __align__(16) short sAh[128*40];
  __shared__ __align__(16) short sAl[128*40];
  __shared__ __align__(16) short sBh[128*40];
  __shared__ __align__(16) short sBl[128*40];
  const int z = blockIdx.z;
  const long aOff = ((long)(z >> aShift)) * aZ;
  const long bOff = ((long)(z >> bShift)) * bZ;
  const long cOff = (long)z * cZ;
  const int i0 = blockIdx.y * 128;
  const int j0 = blockIdx.x * 128;
  const int t = threadIdx.x;
  const int lane = t & 63, w = t >> 6;
  const int wy = w >> 1, wx = w & 1;
  const int il = lane & 15, q = lane >> 4;
  const int kstart = kFromZ ? ((z >> 1) & ~31) : 0;

  f32x4 acc[4][4];
#pragma unroll
  for (int a = 0; a < 4; ++a)
#pragma unroll
    for (int b = 0; b < 4; ++b) acc[a][b] = (f32x4){0.f, 0.f, 0.f, 0.f};

  for (int k0 = kstart; k0 < K; k0 += 32) {
    __syncthreads();
    // ---- stage A ----
    if constexpr (AM == 0) {
      const int r = t >> 1, ks = (t & 1) * 16;
      const size_t g = (size_t)aOff + (size_t)(i0 + r) * lda + k0 + ks;
      *(short8*)&sAh[r*40+ks]   = *(const short8*)(Ah + g);
      *(short8*)&sAh[r*40+ks+8] = *(const short8*)(Ah + g + 8);
      *(short8*)&sAl[r*40+ks]   = *(const short8*)(Al + g);
      *(short8*)&sAl[r*40+ks+8] = *(const short8*)(Al + g + 8);
    } else {  // AM == 2: fp32 [k][i] -> transpose + split
      const int kk0 = 8*w + 2*q;               // even, 0..30
      const float* s0 = Af + aOff + (size_t)(k0 + kk0) * lda + i0 + il;
      const float* s1 = s0 + lda;
#pragma unroll
      for (int c = 0; c < 8; ++c) {
        float v0 = s0[c*16], v1 = s1[c*16];
        ushort h0,l0,h1,l1; split2(v0,h0,l0); split2(v1,h1,l1);
        const int idx = (il + 16*c)*40 + kk0;
        *(uint*)&sAh[idx] = (uint)h0 | ((uint)h1 << 16);
        *(uint*)&sAl[idx] = (uint)l0 | ((uint)l1 << 16);
      }
    }
    // ---- stage B ----
    if constexpr (BM == 0) {
      const int r = t >> 1, ks = (t & 1) * 16;
      const size_t g = (size_t)bOff + (size_t)(j0 + r) * ldb + k0 + ks;
      *(short8*)&sBh[r*40+ks]   = *(const short8*)(Bh + g);
      *(short8*)&sBh[r*40+ks+8] = *(const short8*)(Bh + g + 8);
      *(short8*)&sBl[r*40+ks]   = *(const short8*)(Bl + g);
      *(short8*)&sBl[r*40+ks+8] = *(const short8*)(Bl + g + 8);
    } else {  // BM == 1: fp32 [j][k] -> split
      const int r = t >> 1, ks = (t & 1) * 16;
      const float* src = Bf + bOff + (size_t)(j0 + r) * ldb + k0 + ks;
#pragma unroll
      for (int jj = 0; jj < 4; ++jj) {
        float4 f = *(const float4*)(src + 4*jj);
        ushort h0,l0,h1,l1,h2,l2,h3,l3;
        split2(f.x,h0,l0); split2(f.y,h1,l1); split2(f.z,h2,l2); split2(f.w,h3,l3);
        *(ushort4*)&sBh[r*40+ks+4*jj] = make_ushort4(h0,h1,h2,h3);
        *(ushort4*)&sBl[r*40+ks+4*jj] = make_ushort4(l0,l1,l2,l3);
      }
    }
    __syncthreads();
    // ---- compute: 16 tiles x 3 split-MFMAs ----
    short8 afh[4], afl[4];
#pragma unroll
    for (int mi = 0; mi < 4; ++mi) {
      const int row = wy*64 + mi*16 + il;
      afh[mi] = *(const short8*)&sAh[row*40 + q*8];
      afl[mi] = *(const short8*)&sAl[row*40 + q*8];
    }
#pragma unroll
    for (int nj = 0; nj < 4; ++nj) {
      const int row = wx*64 + nj*16 + il;
      short8 bfh = *(const short8*)&sBh[row*40 + q*8];
      short8 bfl = *(const short8*)&sBl[row*40 + q*8];
#pragma unroll
      for (int mi = 0; mi < 4; ++mi) {
        acc[mi][nj] = __builtin_amdgcn_mfma_f32_16x16x32_bf16(afh[mi], bfh, acc[mi][nj], 0, 0, 0);
        acc[mi][nj] = __builtin_amdgcn_mfma_f32_16x16x32_bf16(afh[mi], bfl, acc[mi][nj], 0, 0, 0);
        acc[mi][nj] = __builtin_amdgcn_mfma_f32_16x16x32_bf16(afl[mi], bfh, acc[mi][nj], 0, 0, 0);
      }
    }
  }
  // ---- epilogue: D col = lane&15 (N), row = q*4+r (M) ----
#pragma unroll
  for (int mi = 0; mi < 4; ++mi)
#pragma unroll
    for (int nj = 0; nj < 4; ++nj)
#pragma unroll
      for (int r = 0; r < 4; ++r) {
        const long gi = i0 + wy*64 + mi*16 + q*4 + r;
        const long gj = j0 + wx*64 + nj*16 + il;
        C[cOff + gi*ldc + cColOff + gj] = acc[mi][nj][r];
      }
}

// ---------------- K3: per-coefficient channel mixing (fp32, unchanged) -------
__global__ __launch_bounds__(256) void k_stagec(const float* __restrict__ spec,
                                                const float* __restrict__ w,
                                                float* __restrict__ outb) {
  const int cb = blockIdx.x, l = blockIdx.y;
  if (cb * 16 > l) return;
  __shared__ float s_spec[32 * 257];
  __shared__ float s_w[256 * 33];
  const int t = threadIdx.x;
  const int c = t & 31, og = t >> 5;
  const size_t x0 = 258u * l + cb * 32;
  for (int cc = 0; cc < 32; ++cc)
    s_spec[cc * 257 + t] = spec[(size_t)(cb * 32 + cc) * 32768 + l * 256 + t];
  float acc[8][4] = {{0.f}};
  const int lr = t >> 4;
  const int lq = (t & 15) * 2;
  for (int isub = 0; isub < 4; ++isub) {
    __syncthreads();
    for (int pass = 0; pass < 16; ++pass) {
      const int rho = pass * 16 + lr;
      const int io = (isub * 8 + (rho >> 5)) * 32 + (rho & 31);
      const float2 wv = *(const float2*)&w[(size_t)io * 33024 + x0 + lq];
      s_w[rho * 33 + lq]     = wv.x;
      s_w[rho * 33 + lq + 1] = wv.y;
    }
    __syncthreads();
#pragma unroll
    for (int idp = 0; idp < 4; ++idp) {
      const int i0 = isub * 8 + idp * 2;
      const int r0 = idp * 64;
      float2 sv[8];
#pragma unroll
      for (int b = 0; b < 8; ++b)
        sv[b] = *(const float2*)&s_spec[c * 257 + b * 32 + i0];
      float wv0[4], wv1[4];
#pragma unroll
      for (int od = 0; od < 4; ++od) {
        wv0[od] = s_w[(r0 + og * 4 + od) * 33 + c];
        wv1[od] = s_w[(r0 + 32 + og * 4 + od) * 33 + c];
      }
#pragma unroll
      for (int b = 0; b < 8; ++b)
#pragma unroll
        for (int od = 0; od < 4; ++od)
          acc[b][od] = fmaf(sv[b].x, wv0[od], fmaf(sv[b].y, wv1[od], acc[b][od]));
    }
  }
  __syncthreads();
#pragma unroll
  for (int b = 0; b < 8; ++b)
#pragma unroll
    for (int od = 0; od < 4; ++od)
      s_w[c * 257 + b * 32 + og * 4 + od] = acc[b][od];
  __syncthreads();
  for (int cc = 0; cc < 32; ++cc)
    outb[(size_t)(cb * 32 + cc) * 32768 + l * 256 + t] = s_w[cc * 257 + t];
}

// ---------------- launch ----------------
extern "C" void kernel_launch(void* const* d_in, const int* in_sizes, int n_in,
                              void* d_out, int out_size, void* d_ws, size_t ws_size,
                              hipStream_t stream) {
  const float* x = (const float*)d_in[0];   // (8,32,256,256)
  const float* w = (const float*)d_in[1];   // (32,32,33024)
  float* y = (float*)d_out;                 // (8,32,256,256)
  char* ws = (char*)d_ws;

  // workspace layout (bytes); total = 168,296,448 (same as validated R2 size)
  ushort* Th   = (ushort*)(ws + 0);          //  256*256 bf16
  ushort* Tl   = (ushort*)(ws + 131072);
  ushort* TiTh = (ushort*)(ws + 262144);     //  [n][mc]
  ushort* TiTl = (ushort*)(ws + 393216);
  ushort* PWh  = (ushort*)(ws + 524288);     //  [m][l][k]  8 MB
  ushort* PWl  = (ushort*)(ws + 8912896);
  ushort* PTh  = (ushort*)(ws + 17301504);   //  [m][k][l]  8 MB
  ushort* PTl  = (ushort*)(ws + 25690112);
  float* XHhalf= (float*)(ws + 34078720);    //  256 x 32768 fp32 (33.5 MB); outb overlays
  float* outb  = XHhalf;
  float* spec  = (float*)(ws + 67633152);    //  [mc][l][bc] fp32 (33.5 MB)
  float* XM    = (float*)(ws + 101187584);   //  [mc][bo*256+k] fp32 (67 MB)

  // K0: tables
  k_tables<<<dim3(129), dim3(256), 0, stream>>>(Th, Tl, TiTh, TiTl, PWh, PWl, PTh, PTl);

  for (int half = 0; half < 2; ++half) {
    // K1: fwd DFT  XHhalf[mc][row] = sum_n T[mc][n] * x[rowg][n]; M=256, N=32768, K=256
    mfma_gemm<0,1><<<dim3(256, 2, 1), dim3(256), 0, stream>>>(
        Th, Tl, nullptr, nullptr, nullptr, x + (size_t)half * 8388608, XHhalf,
        256, 256, 32768, 256, 0L, 0, 0L, 0, 0L, 0, 0);
    // K2: fwd Legendre per z=mc: spec[z][l][bc] = sum_k PW[m][l][k]*XHhalf[z][bc][k]
    mfma_gemm<0,1><<<dim3(1, 1, 256), dim3(256), 0, stream>>>(
        PWh, PWl, nullptr, nullptr, nullptr, XHhalf, spec,
        256, 256, 256, 256, 32768L, 1, 32768L, 0, 32768L, half * 128, 0);
  }

  // K3: channel mixing (fp32)
  k_stagec<<<dim3(8, 128), dim3(256), 0, stream>>>(spec, w, outb);

  // K4: inv Legendre per z=mc: XM[z][bo*256+kl] = sum_l outb[z][l][bo]*PT[m][kl][l]
  mfma_gemm<2,0><<<dim3(2, 2, 256), dim3(256), 0, stream>>>(
      nullptr, nullptr, outb, PTh, PTl, nullptr, XM,
      256, 128, 256, 128, 32768L, 0, 32768L, 1, 65536L, 0, 1);

  // K5: inv DFT: y[row][n] = sum_mc XM[mc][row]*TiT[n][mc]
  mfma_gemm<2,0><<<dim3(2, 512, 1), dim3(256), 0, stream>>>(
      nullptr, nullptr, XM, TiTh, TiTl, nullptr, y,
      65536, 256, 256, 256, 0L, 0, 0L, 0, 0L, 0, 0);
}

// Round 2
// 420.969 us; speedup vs baseline: 1.1877x; 1.1877x over previous
//
#include <hip/hip_runtime.h>

// SphericalConvMHF — round 5: fast k_tables.
// Pipeline: K0 tables(hi/lo bf16) -> K1 fwd-DFT (MFMA) -> K2 fwd-Legendre (MFMA)
//   -> K3 channel-mix (fp32) -> K4 inv-Legendre (MFMA) -> K5 inv-DFT (MFMA).
// R5 change (counter-driven): k_tables was 110 µs (22% of total), latency-bound
// fp64 (127 serial cos/thread, redundant per-block sqrt/div) with ~10x HBM
// write amplification (343 MB measured vs 33 MB ideal, partial-line scatters).
// New k_tables: LDS-hoisted cos/coef/ratio/a/b tables (3 fp64 transcendentals
// per thread instead of 129), mul-only serial chains, register-buffered PT/TiT
// rows stored as aligned uint4 (full-line writes). Numerics stay fp64; only
// reassociation-level (~1e-13) deltas vs the original recurrence.
// Everything else identical to the verified 499 µs R3 kernel.

typedef __attribute__((ext_vector_type(8))) short short8;
typedef __attribute__((ext_vector_type(4))) float f32x4;

__device__ __forceinline__ ushort bf16_rtn(float v) {
  uint u = __float_as_uint(v);
  return (ushort)((u + 0x7FFFu + ((u >> 16) & 1u)) >> 16);
}
__device__ __forceinline__ void split2(float v, ushort& h, ushort& l) {
  h = bf16_rtn(v);
  float hf = __uint_as_float(((uint)h) << 16);
  l = bf16_rtn(v - hf);
}

// ---------------- K0: table generation (fp64, LDS-hoisted, packed writes) ----
__global__ __launch_bounds__(256) void k_tables(
    ushort* __restrict__ Th, ushort* __restrict__ Tl,
    ushort* __restrict__ TiTh, ushort* __restrict__ TiTl,
    ushort* __restrict__ PWh, ushort* __restrict__ PWl,
    ushort* __restrict__ PTh, ushort* __restrict__ PTl) {
  const double PI = 3.14159265358979323846264338327950288;
  const int t = threadIdx.x;
  const int m = blockIdx.x;
  __shared__ double sCos[256];   // cos table (256-grid for trig block, 255-grid for wq)
  __shared__ double sCoef[128];  // 2/(4kk^2-1)
  __shared__ double sRatio[128]; // (2mm+1)/(2mm)
  __shared__ double sA[128], sB[128];

  if (m == 128) {             // trig tables: T[mc][n] and TiT[n][mc]
    const double scale = 2.0 * PI / 256.0;
    sCos[t] = cos(scale * (double)t);
    __syncthreads();
    const int n = t;
    // 8 chunks of 16 mm-values; TiT row buffered in registers, stored as uint4.
    for (int ch = 0; ch < 8; ++ch) {
      uint tih[8], til[8];
#pragma unroll
      for (int j = 0; j < 16; ++j) {
        const int mm = ch * 16 + j;
        const int r = (mm * n) & 255;
        const double c = sCos[r];
        const double s = sCos[(r + 192) & 255];  // sin(2pi r/256) = cos(2pi (r-64)/256)
        const double wm = (mm == 0) ? 1.0 : 2.0;
        ushort h, l;
        split2((float)(scale * c), h, l);  Th[(2*mm)*256+n]=h;   Tl[(2*mm)*256+n]=l;
        split2((float)(-scale * s), h, l); Th[(2*mm+1)*256+n]=h; Tl[(2*mm+1)*256+n]=l;
        ushort h2, l2b, h3, l3;
        split2((float)(wm * c), h2, l2b);
        split2((float)(-wm * s), h3, l3);
        if (j & 1) { tih[j>>1] |= ((uint)h2 << 16*0) << 0, tih[j>>1] = tih[j>>1]; }
        // pack pairs: even j initializes low half, odd j fills high half
        if ((j & 1) == 0) { tih[j>>1] = (uint)h2 | ((uint)h3 << 16); til[j>>1] = (uint)l2b | ((uint)l3 << 16); }
        else              { /* placeholder (handled below) */ }
        // NOTE: each mm produces TWO consecutive ushorts (cols 2mm, 2mm+1),
        // i.e. one full uint per j — so pack directly:
        tih[j>>1] = tih[j>>1]; // no-op to keep structure clear
        (void)0;
        // overwrite with the correct direct packing:
        if (true) { uint hv = (uint)h2 | ((uint)h3 << 16);
                    uint lv = (uint)l2b | ((uint)l3 << 16);
                    if ((j & 1) == 0) { tih[j>>1] = hv; til[j>>1] = lv; }
                    else { /* odd j is a second uint: store in odd slot */ }
        }
        // Simpler: since each j is one uint, use 16 slots.
        (void)0;
      }
      // --- the loop above is replaced by a clean version below ---
      (void)tih; (void)til;
      uint th16[16], tl16[16];
#pragma unroll
      for (int j = 0; j < 16; ++j) {
        const int mm = ch * 16 + j;
        const int r = (mm * n) & 255;
        const double c = sCos[r];
        const double s = sCos[(r + 192) & 255];
        const double wm = (mm == 0) ? 1.0 : 2.0;
        ushort h2, l2b, h3, l3;
        split2((float)(wm * c), h2, l2b);
        split2((float)(-wm * s), h3, l3);
        th16[j] = (uint)h2 | ((uint)h3 << 16);
        tl16[j] = (uint)l2b | ((uint)l3 << 16);
      }
      const int base = n * 256 + ch * 32;   // ushort index
#pragma unroll
      for (int q4 = 0; q4 < 4; ++q4) {
        *(uint4*)(TiTh + base + q4 * 8) = make_uint4(th16[4*q4], th16[4*q4+1], th16[4*q4+2], th16[4*q4+3]);
        *(uint4*)(TiTl + base + q4 * 8) = make_uint4(tl16[4*q4], tl16[4*q4+1], tl16[4*q4+2], tl16[4*q4+3]);
      }
    }
    return;
  }

  // ---- cooperative k-independent tables (per block; m is block-uniform) ----
  const double scale255 = 2.0 * PI / 255.0;
  if (t < 255) sCos[t] = cos(scale255 * (double)t);
  if (t >= 1 && t < 128) {
    const double dt = (double)t;
    sCoef[t]  = 2.0 / (4.0 * dt * dt - 1.0);
    sRatio[t] = (2.0 * dt + 1.0) / (2.0 * dt);
    if (t >= m + 2) {
      const double dl = dt, dm = (double)m;
      sA[t] = sqrt((4.0*dl*dl - 1.0) / (dl*dl - dm*dm));
      sB[t] = sqrt(((dl-1.0)*(dl-1.0) - dm*dm) / (4.0*(dl-1.0)*(dl-1.0) - 1.0));
    }
  }
  __syncthreads();

  const int k = t;  // latitude index
  const double tj = PI * (double)k / 255.0;
  // wq: ssum via LDS cos table — cos(2*tj*kk) = cos(2pi*(k*kk mod 255)/255)
  double ssum = 0.0;
  {
    int r = 0;
    for (int kk = 1; kk <= 127; ++kk) {
      r += k; if (r >= 255) r -= 255;
      ssum += sCoef[kk] * sCos[r];
    }
  }
  const double cj = (k == 0 || k == 255) ? 1.0 : 2.0;
  const double wq = cj / 255.0 * (1.0 - ssum);
  const double ct = cos(tj), st = sin(tj);
  // pmm = (1/sqrt(4pi)) * (-st)^m * sqrt(prod_{mm<=m} (2mm+1)/(2mm))
  double prod = 1.0, stp = 1.0;
  for (int mm = 1; mm <= m; ++mm) { prod *= sRatio[mm]; stp *= -st; }
  const double pmm = (1.0 / sqrt(4.0 * PI)) * sqrt(prod) * stp;
  const double sq2m3 = sqrt(2.0 * (double)m + 3.0);

  const size_t pwB = (size_t)m * 32768;                   // [l][k]
  const size_t ptB = (size_t)m * 32768 + (size_t)k * 128; // [k][l]
  double plm1 = 0.0, plm2 = 0.0;
  for (int lc0 = 0; lc0 < 128; lc0 += 16) {
    uint hq[8], lq[8];
#pragma unroll
    for (int j = 0; j < 16; ++j) {
      const int l = lc0 + j;
      double val;
      if (l < m)           val = 0.0;
      else if (l == m)     val = pmm;
      else if (l == m + 1) val = sq2m3 * ct * pmm;
      else                 val = sA[l] * (ct * plm1 - sB[l] * plm2);
      plm2 = plm1; plm1 = val;
      ushort h, lo; split2((float)val, h, lo);
      if ((j & 1) == 0) { hq[j>>1] = (uint)h; lq[j>>1] = (uint)lo; }
      else              { hq[j>>1] |= ((uint)h) << 16; lq[j>>1] |= ((uint)lo) << 16; }
      ushort hw, lw; split2((float)(val * wq), hw, lw);
      PWh[pwB + (size_t)l * 256 + k] = hw;   // coalesced across threads per l
      PWl[pwB + (size_t)l * 256 + k] = lw;
    }
    // PT row chunk: 32 B per array, contiguous, 16B-aligned (ptB*2 is 256B-aligned)
    *(uint4*)(PTh + ptB + lc0)     = make_uint4(hq[0], hq[1], hq[2], hq[3]);
    *(uint4*)(PTh + ptB + lc0 + 8) = make_uint4(hq[4], hq[5], hq[6], hq[7]);
    *(uint4*)(PTl + ptB + lc0)     = make_uint4(lq[0], lq[1], lq[2], lq[3]);
    *(uint4*)(PTl + ptB + lc0 + 8) = make_uint4(lq[4], lq[5], lq[6], lq[7]);
  }
}

// ---------------- split-bf16 MFMA GEMM ----------------
// C[i][j] = sum_k A[i][k]*B[j][k]. Block 128x128, 4 waves (64x64 each), BK=32.
// AM: 0 = A from pre-split bf16 [i][k]; 2 = A from fp32 [k][i] (transpose+cvt).
// BM: 0 = B from pre-split bf16 [j][k]; 1 = B from fp32 [j][k] (cvt).
// LDS pitch 40 shorts (80 B): 16B-aligned rows, ~2-way bank aliasing (free).
template<int AM, int BM>
__global__ __launch_bounds__(256) void mfma_gemm(
    const ushort* __restrict__ Ah, const ushort* __restrict__ Al, const float* __restrict__ Af,
    const ushort* __restrict__ Bh, const ushort* __restrict__ Bl, const float* __restrict__ Bf,
    float* __restrict__ C,
    int lda, int ldb, int ldc, int K,
    long aZ, int aShift, long bZ, int bShift, long cZ, int cColOff, int kFromZ)
{
  __shared__ __align__(16) short sAh[128*40];
  __shared__ __align__(16) short sAl[128*40];
  __shared__ __align__(16) short sBh[128*40];
  __shared__ __align__(16) short sBl[128*40];
  const int z = blockIdx.z;
  const long aOff = ((long)(z >> aShift)) * aZ;
  const long bOff = ((long)(z >> bShift)) * bZ;
  const long cOff = (long)z * cZ;
  const int i0 = blockIdx.y * 128;
  const int j0 = blockIdx.x * 128;
  const int t = threadIdx.x;
  const int lane = t & 63, w = t >> 6;
  const int wy = w >> 1, wx = w & 1;
  const int il = lane & 15, q = lane >> 4;
  const int kstart = kFromZ ? ((z >> 1) & ~31) : 0;

  f32x4 acc[4][4];
#pragma unroll
  for (int a = 0; a < 4; ++a)
#pragma unroll
    for (int b = 0; b < 4; ++b) acc[a][b] = (f32x4){0.f, 0.f, 0.f, 0.f};

  for (int k0 = kstart; k0 < K; k0 += 32) {
    __syncthreads();
    // ---- stage A ----
    if constexpr (AM == 0) {
      const int r = t >> 1, ks = (t & 1) * 16;
      const size_t g = (size_t)aOff + (size_t)(i0 + r) * lda + k0 + ks;
      *(short8*)&sAh[r*40+ks]   = *(const short8*)(Ah + g);
      *(short8*)&sAh[r*40+ks+8] = *(const short8*)(Ah + g + 8);
      *(short8*)&sAl[r*40+ks]   = *(const short8*)(Al + g);
      *(short8*)&sAl[r*40+ks+8] = *(const short8*)(Al + g + 8);
    } else {  // AM == 2: fp32 [k][i] -> transpose + split
      const int kk0 = 8*w + 2*q;               // even, 0..30
      const float* s0 = Af + aOff + (size_t)(k0 + kk0) * lda + i0 + il;
      const float* s1 = s0 + lda;
#pragma unroll
      for (int c = 0; c < 8; ++c) {
        float v0 = s0[c*16], v1 = s1[c*16];
        ushort h0,l0,h1,l1; split2(v0,h0,l0); split2(v1,h1,l1);
        const int idx = (il + 16*c)*40 + kk0;
        *(uint*)&sAh[idx] = (uint)h0 | ((uint)h1 << 16);
        *(uint*)&sAl[idx] = (uint)l0 | ((uint)l1 << 16);
      }
    }
    // ---- stage B ----
    if constexpr (BM == 0) {
      const int r = t >> 1, ks = (t & 1) * 16;
      const size_t g = (size_t)bOff + (size_t)(j0 + r) * ldb + k0 + ks;
      *(short8*)&sBh[r*40+ks]   = *(const short8*)(Bh + g);
      *(short8*)&sBh[r*40+ks+8] = *(const short8*)(Bh + g + 8);
      *(short8*)&sBl[r*40+ks]   = *(const short8*)(Bl + g);
      *(short8*)&sBl[r*40+ks+8] = *(const short8*)(Bl + g + 8);
    } else {  // BM == 1: fp32 [j][k] -> split
      const int r = t >> 1, ks = (t & 1) * 16;
      const float* src = Bf + bOff + (size_t)(j0 + r) * ldb + k0 + ks;
#pragma unroll
      for (int jj = 0; jj < 4; ++jj) {
        float4 f = *(const float4*)(src + 4*jj);
        ushort h0,l0,h1,l1,h2,l2,h3,l3;
        split2(f.x,h0,l0); split2(f.y,h1,l1); split2(f.z,h2,l2); split2(f.w,h3,l3);
        *(ushort4*)&sBh[r*40+ks+4*jj] = make_ushort4(h0,h1,h2,h3);
        *(ushort4*)&sBl[r*40+ks+4*jj] = make_ushort4(l0,l1,l2,l3);
      }
    }
    __syncthreads();
    // ---- compute: 16 tiles x 3 split-MFMAs ----
    short8 afh[4], afl[4];
#pragma unroll
    for (int mi = 0; mi < 4; ++mi) {
      const int row = wy*64 + mi*16 + il;
      afh[mi] = *(const short8*)&sAh[row*40 + q*8];
      afl[mi] = *(const short8*)&sAl[row*40 + q*8];
    }
#pragma unroll
    for (int nj = 0; nj < 4; ++nj) {
      const int row = wx*64 + nj*16 + il;
      short8 bfh = *(const short8*)&sBh[row*40 + q*8];
      short8 bfl = *(const short8*)&sBl[row*40 + q*8];
#pragma unroll
      for (int mi = 0; mi < 4; ++mi) {
        acc[mi][nj] = __builtin_amdgcn_mfma_f32_16x16x32_bf16(afh[mi], bfh, acc[mi][nj], 0, 0, 0);
        acc[mi][nj] = __builtin_amdgcn_mfma_f32_16x16x32_bf16(afh[mi], bfl, acc[mi][nj], 0, 0, 0);
        acc[mi][nj] = __builtin_amdgcn_mfma_f32_16x16x32_bf16(afl[mi], bfh, acc[mi][nj], 0, 0, 0);
      }
    }
  }
  // ---- epilogue: D col = lane&15 (N), row = q*4+r (M) ----
#pragma unroll
  for (int mi = 0; mi < 4; ++mi)
#pragma unroll
    for (int nj = 0; nj < 4; ++nj)
#pragma unroll
      for (int r = 0; r < 4; ++r) {
        const long gi = i0 + wy*64 + mi*16 + q*4 + r;
        const long gj = j0 + wx*64 + nj*16 + il;
        C[cOff + gi*ldc + cColOff + gj] = acc[mi][nj][r];
      }
}

// ---------------- K3: per-coefficient channel mixing (fp32, unchanged) -------
__global__ __launch_bounds__(256) void k_stagec(const float* __restrict__ spec,
                                                const float* __restrict__ w,
                                                float* __restrict__ outb) {
  const int cb = blockIdx.x, l = blockIdx.y;
  if (cb * 16 > l) return;
  __shared__ float s_spec[32 * 257];
  __shared__ float s_w[256 * 33];
  const int t = threadIdx.x;
  const int c = t & 31, og = t >> 5;
  const size_t x0 = 258u * l + cb * 32;
  for (int cc = 0; cc < 32; ++cc)
    s_spec[cc * 257 + t] = spec[(size_t)(cb * 32 + cc) * 32768 + l * 256 + t];
  float acc[8][4] = {{0.f}};
  const int lr = t >> 4;
  const int lq = (t & 15) * 2;
  for (int isub = 0; isub < 4; ++isub) {
    __syncthreads();
    for (int pass = 0; pass < 16; ++pass) {
      const int rho = pass * 16 + lr;
      const int io = (isub * 8 + (rho >> 5)) * 32 + (rho & 31);
      const float2 wv = *(const float2*)&w[(size_t)io * 33024 + x0 + lq];
      s_w[rho * 33 + lq]     = wv.x;
      s_w[rho * 33 + lq + 1] = wv.y;
    }
    __syncthreads();
#pragma unroll
    for (int idp = 0; idp < 4; ++idp) {
      const int i0 = isub * 8 + idp * 2;
      const int r0 = idp * 64;
      float2 sv[8];
#pragma unroll
      for (int b = 0; b < 8; ++b)
        sv[b] = *(const float2*)&s_spec[c * 257 + b * 32 + i0];
      float wv0[4], wv1[4];
#pragma unroll
      for (int od = 0; od < 4; ++od) {
        wv0[od] = s_w[(r0 + og * 4 + od) * 33 + c];
        wv1[od] = s_w[(r0 + 32 + og * 4 + od) * 33 + c];
      }
#pragma unroll
      for (int b = 0; b < 8; ++b)
#pragma unroll
        for (int od = 0; od < 4; ++od)
          acc[b][od] = fmaf(sv[b].x, wv0[od], fmaf(sv[b].y, wv1[od], acc[b][od]));
    }
  }
  __syncthreads();
#pragma unroll
  for (int b = 0; b < 8; ++b)
#pragma unroll
    for (int od = 0; od < 4; ++od)
      s_w[c * 257 + b * 32 + og * 4 + od] = acc[b][od];
  __syncthreads();
  for (int cc = 0; cc < 32; ++cc)
    outb[(size_t)(cb * 32 + cc) * 32768 + l * 256 + t] = s_w[cc * 257 + t];
}

// ---------------- launch ----------------
extern "C" void kernel_launch(void* const* d_in, const int* in_sizes, int n_in,
                              void* d_out, int out_size, void* d_ws, size_t ws_size,
                              hipStream_t stream) {
  const float* x = (const float*)d_in[0];   // (8,32,256,256)
  const float* w = (const float*)d_in[1];   // (32,32,33024)
  float* y = (float*)d_out;                 // (8,32,256,256)
  char* ws = (char*)d_ws;

  // workspace layout (bytes); total = 168,296,448 (same as validated R2 size)
  ushort* Th   = (ushort*)(ws + 0);          //  256*256 bf16
  ushort* Tl   = (ushort*)(ws + 131072);
  ushort* TiTh = (ushort*)(ws + 262144);     //  [n][mc]
  ushort* TiTl = (ushort*)(ws + 393216);
  ushort* PWh  = (ushort*)(ws + 524288);     //  [m][l][k]  8 MB
  ushort* PWl  = (ushort*)(ws + 8912896);
  ushort* PTh  = (ushort*)(ws + 17301504);   //  [m][k][l]  8 MB
  ushort* PTl  = (ushort*)(ws + 25690112);
  float* XHhalf= (float*)(ws + 34078720);    //  256 x 32768 fp32 (33.5 MB); outb overlays
  float* outb  = XHhalf;
  float* spec  = (float*)(ws + 67633152);    //  [mc][l][bc] fp32 (33.5 MB)
  float* XM    = (float*)(ws + 101187584);   //  [mc][bo*256+k] fp32 (67 MB)

  // K0: tables
  k_tables<<<dim3(129), dim3(256), 0, stream>>>(Th, Tl, TiTh, TiTl, PWh, PWl, PTh, PTl);

  for (int half = 0; half < 2; ++half) {
    // K1: fwd DFT  XHhalf[mc][row] = sum_n T[mc][n] * x[rowg][n]; M=256, N=32768, K=256
    mfma_gemm<0,1><<<dim3(256, 2, 1), dim3(256), 0, stream>>>(
        Th, Tl, nullptr, nullptr, nullptr, x + (size_t)half * 8388608, XHhalf,
        256, 256, 32768, 256, 0L, 0, 0L, 0, 0L, 0, 0);
    // K2: fwd Legendre per z=mc: spec[z][l][bc] = sum_k PW[m][l][k]*XHhalf[z][bc][k]
    mfma_gemm<0,1><<<dim3(1, 1, 256), dim3(256), 0, stream>>>(
        PWh, PWl, nullptr, nullptr, nullptr, XHhalf, spec,
        256, 256, 256, 256, 32768L, 1, 32768L, 0, 32768L, half * 128, 0);
  }

  // K3: channel mixing (fp32)
  k_stagec<<<dim3(8, 128), dim3(256), 0, stream>>>(spec, w, outb);

  // K4: inv Legendre per z=mc: XM[z][bo*256+kl] = sum_l outb[z][l][bo]*PT[m][kl][l]
  mfma_gemm<2,0><<<dim3(2, 2, 256), dim3(256), 0, stream>>>(
      nullptr, nullptr, outb, PTh, PTl, nullptr, XM,
      256, 128, 256, 128, 32768L, 0, 32768L, 1, 65536L, 0, 1);

  // K5: inv DFT: y[row][n] = sum_mc XM[mc][row]*TiT[n][mc]
  mfma_gemm<2,0><<<dim3(2, 512, 1), dim3(256), 0, stream>>>(
      nullptr, nullptr, XM, TiTh, TiTl, nullptr, y,
      65536, 256, 256, 256, 0L, 0, 0L, 0, 0L, 0, 0);
}

// Round 3
// 414.722 us; speedup vs baseline: 1.2056x; 1.0151x over previous
//
#include <hip/hip_runtime.h>

// SphericalConvMHF — round 6: XH as pre-split bf16, merged launches, K2 sparsity.
// Pipeline: K0 tables -> K1 fwd-DFT (MFMA, writes XHh/XHl split-bf16)
//   -> K2 fwd-Legendre (MFMA <0,0>, mi-tile skip for l<m) -> K3 channel-mix
//   (fp32, in-place on spec) -> K4 inv-Legendre -> K5 inv-DFT.
// R6 changes (counter/arithmetic-driven):
//  * K2 was 1 block/CU (latency-exposed) with fp32->split cvt (~100 VALU/thread/
//    k-step) on the critical path, and 44% of its MFMA tiles compute zeros
//    (PW rows l<m). Fix: XH stored as split-bf16 pair by K1's epilogue (same
//    values K2 derived -> bit-identical), K2 single launch grid(2,1,256)
//    (2 blocks/CU), wave-uniform mi-tile skip below l=m.
//  * Workspace re-layout: outb aliases spec (K3 is per-block in-place-safe:
//    reads complete before writes, footprints identical); XM overlays the dead
//    XH region. Total 134.7 MB < 168 MB, so no more 2-half split: K1 and K2
//    are single launches.
// Poison safety: K2 writes ALL spec rows (zeros where l<m); K3-skipped planes
// hold finite spec values that multiply PT==0 in K4.

typedef __attribute__((ext_vector_type(8))) short short8;
typedef __attribute__((ext_vector_type(4))) float f32x4;

__device__ __forceinline__ ushort bf16_rtn(float v) {
  uint u = __float_as_uint(v);
  return (ushort)((u + 0x7FFFu + ((u >> 16) & 1u)) >> 16);
}
__device__ __forceinline__ void split2(float v, ushort& h, ushort& l) {
  h = bf16_rtn(v);
  float hf = __uint_as_float(((uint)h) << 16);
  l = bf16_rtn(v - hf);
}

// ---------------- K0: table generation (fp64, LDS-hoisted, packed writes) ----
__global__ __launch_bounds__(256) void k_tables(
    ushort* __restrict__ Th, ushort* __restrict__ Tl,
    ushort* __restrict__ TiTh, ushort* __restrict__ TiTl,
    ushort* __restrict__ PWh, ushort* __restrict__ PWl,
    ushort* __restrict__ PTh, ushort* __restrict__ PTl) {
  const double PI = 3.14159265358979323846264338327950288;
  const int t = threadIdx.x;
  const int m = blockIdx.x;
  __shared__ double sCos[256];   // cos table (256-grid for trig block, 255-grid for wq)
  __shared__ double sCoef[128];  // 2/(4kk^2-1)
  __shared__ double sRatio[128]; // (2mm+1)/(2mm)
  __shared__ double sA[128], sB[128];

  if (m == 128) {             // trig tables: T[mc][n] and TiT[n][mc]
    const double scale = 2.0 * PI / 256.0;
    sCos[t] = cos(scale * (double)t);
    __syncthreads();
    const int n = t;
    for (int ch = 0; ch < 8; ++ch) {
      uint th16[16], tl16[16];
#pragma unroll
      for (int j = 0; j < 16; ++j) {
        const int mm = ch * 16 + j;
        const int r = (mm * n) & 255;
        const double c = sCos[r];
        const double s = sCos[(r + 192) & 255];  // sin(2pi r/256) = cos(2pi (r-64)/256)
        const double wm = (mm == 0) ? 1.0 : 2.0;
        ushort h, l;
        split2((float)(scale * c), h, l);  Th[(2*mm)*256+n]=h;   Tl[(2*mm)*256+n]=l;
        split2((float)(-scale * s), h, l); Th[(2*mm+1)*256+n]=h; Tl[(2*mm+1)*256+n]=l;
        ushort h2, l2b, h3, l3;
        split2((float)(wm * c), h2, l2b);
        split2((float)(-wm * s), h3, l3);
        th16[j] = (uint)h2 | ((uint)h3 << 16);
        tl16[j] = (uint)l2b | ((uint)l3 << 16);
      }
      const int base = n * 256 + ch * 32;   // ushort index
#pragma unroll
      for (int q4 = 0; q4 < 4; ++q4) {
        *(uint4*)(TiTh + base + q4 * 8) = make_uint4(th16[4*q4], th16[4*q4+1], th16[4*q4+2], th16[4*q4+3]);
        *(uint4*)(TiTl + base + q4 * 8) = make_uint4(tl16[4*q4], tl16[4*q4+1], tl16[4*q4+2], tl16[4*q4+3]);
      }
    }
    return;
  }

  // ---- cooperative k-independent tables (per block; m is block-uniform) ----
  const double scale255 = 2.0 * PI / 255.0;
  if (t < 255) sCos[t] = cos(scale255 * (double)t);
  if (t >= 1 && t < 128) {
    const double dt = (double)t;
    sCoef[t]  = 2.0 / (4.0 * dt * dt - 1.0);
    sRatio[t] = (2.0 * dt + 1.0) / (2.0 * dt);
    if (t >= m + 2) {
      const double dl = dt, dm = (double)m;
      sA[t] = sqrt((4.0*dl*dl - 1.0) / (dl*dl - dm*dm));
      sB[t] = sqrt(((dl-1.0)*(dl-1.0) - dm*dm) / (4.0*(dl-1.0)*(dl-1.0) - 1.0));
    }
  }
  __syncthreads();

  const int k = t;  // latitude index
  const double tj = PI * (double)k / 255.0;
  double ssum = 0.0;
  {
    int r = 0;
    for (int kk = 1; kk <= 127; ++kk) {
      r += k; if (r >= 255) r -= 255;
      ssum += sCoef[kk] * sCos[r];
    }
  }
  const double cj = (k == 0 || k == 255) ? 1.0 : 2.0;
  const double wq = cj / 255.0 * (1.0 - ssum);
  const double ct = cos(tj), st = sin(tj);
  double prod = 1.0, stp = 1.0;
  for (int mm = 1; mm <= m; ++mm) { prod *= sRatio[mm]; stp *= -st; }
  const double pmm = (1.0 / sqrt(4.0 * PI)) * sqrt(prod) * stp;
  const double sq2m3 = sqrt(2.0 * (double)m + 3.0);

  const size_t pwB = (size_t)m * 32768;                   // [l][k]
  const size_t ptB = (size_t)m * 32768 + (size_t)k * 128; // [k][l]
  double plm1 = 0.0, plm2 = 0.0;
  for (int lc0 = 0; lc0 < 128; lc0 += 16) {
    uint hq[8], lq[8];
#pragma unroll
    for (int j = 0; j < 16; ++j) {
      const int l = lc0 + j;
      double val;
      if (l < m)           val = 0.0;
      else if (l == m)     val = pmm;
      else if (l == m + 1) val = sq2m3 * ct * pmm;
      else                 val = sA[l] * (ct * plm1 - sB[l] * plm2);
      plm2 = plm1; plm1 = val;
      ushort h, lo; split2((float)val, h, lo);
      if ((j & 1) == 0) { hq[j>>1] = (uint)h; lq[j>>1] = (uint)lo; }
      else              { hq[j>>1] |= ((uint)h) << 16; lq[j>>1] |= ((uint)lo) << 16; }
      ushort hw, lw; split2((float)(val * wq), hw, lw);
      PWh[pwB + (size_t)l * 256 + k] = hw;   // coalesced across threads per l
      PWl[pwB + (size_t)l * 256 + k] = lw;
    }
    *(uint4*)(PTh + ptB + lc0)     = make_uint4(hq[0], hq[1], hq[2], hq[3]);
    *(uint4*)(PTh + ptB + lc0 + 8) = make_uint4(hq[4], hq[5], hq[6], hq[7]);
    *(uint4*)(PTl + ptB + lc0)     = make_uint4(lq[0], lq[1], lq[2], lq[3]);
    *(uint4*)(PTl + ptB + lc0 + 8) = make_uint4(lq[4], lq[5], lq[6], lq[7]);
  }
}

// ---------------- split-bf16 MFMA GEMM ----------------
// C[i][j] = sum_k A[i][k]*B[j][k]. Block 128x128, 4 waves (64x64 each), BK=32.
// AM: 0 = A from pre-split bf16 [i][k]; 2 = A from fp32 [k][i] (transpose+cvt).
// BM: 0 = B from pre-split bf16 [j][k]; 1 = B from fp32 [j][k] (cvt).
// CM: 0 = fp32 C; 1 = split-bf16 pair (Ch/Cl).
// mSkipFromZ: skip MFMA tiles whose rows are < m = z>>1 (A rows known zero).
// LDS pitch 40 shorts (80 B): 16B-aligned rows, ~2-way bank aliasing (free).
template<int AM, int BM, int CM>
__global__ __launch_bounds__(256) void mfma_gemm(
    const ushort* __restrict__ Ah, const ushort* __restrict__ Al, const float* __restrict__ Af,
    const ushort* __restrict__ Bh, const ushort* __restrict__ Bl, const float* __restrict__ Bf,
    float* __restrict__ C, ushort* __restrict__ Ch, ushort* __restrict__ Cl,
    int lda, int ldb, int ldc, int K,
    long aZ, int aShift, long bZ, int bShift, long cZ, int cColOff,
    int kFromZ, int mSkipFromZ)
{
  __shared__ __align__(16) short sAh[128*40];
  __shared__ __align__(16) short sAl[128*40];
  __shared__ __align__(16) short sBh[128*40];
  __shared__ __align__(16) short sBl[128*40];
  const int z = blockIdx.z;
  const long aOff = ((long)(z >> aShift)) * aZ;
  const long bOff = ((long)(z >> bShift)) * bZ;
  const long cOff = (long)z * cZ;
  const int i0 = blockIdx.y * 128;
  const int j0 = blockIdx.x * 128;
  const int t = threadIdx.x;
  const int lane = t & 63, w = t >> 6;
  const int wy = w >> 1, wx = w & 1;
  const int il = lane & 15, q = lane >> 4;
  const int kstart = kFromZ ? ((z >> 1) & ~31) : 0;
  const int nsk = mSkipFromZ ? ((z >> 1) >> 4) : 0;   // fully-zero 16-row tiles

  f32x4 acc[4][4];
#pragma unroll
  for (int a = 0; a < 4; ++a)
#pragma unroll
    for (int b = 0; b < 4; ++b) acc[a][b] = (f32x4){0.f, 0.f, 0.f, 0.f};

  for (int k0 = kstart; k0 < K; k0 += 32) {
    __syncthreads();
    // ---- stage A ----
    if constexpr (AM == 0) {
      const int r = t >> 1, ks = (t & 1) * 16;
      const size_t g = (size_t)aOff + (size_t)(i0 + r) * lda + k0 + ks;
      *(short8*)&sAh[r*40+ks]   = *(const short8*)(Ah + g);
      *(short8*)&sAh[r*40+ks+8] = *(const short8*)(Ah + g + 8);
      *(short8*)&sAl[r*40+ks]   = *(const short8*)(Al + g);
      *(short8*)&sAl[r*40+ks+8] = *(const short8*)(Al + g + 8);
    } else {  // AM == 2: fp32 [k][i] -> transpose + split
      const int kk0 = 8*w + 2*q;               // even, 0..30
      const float* s0 = Af + aOff + (size_t)(k0 + kk0) * lda + i0 + il;
      const float* s1 = s0 + lda;
#pragma unroll
      for (int c = 0; c < 8; ++c) {
        float v0 = s0[c*16], v1 = s1[c*16];
        ushort h0,l0,h1,l1; split2(v0,h0,l0); split2(v1,h1,l1);
        const int idx = (il + 16*c)*40 + kk0;
        *(uint*)&sAh[idx] = (uint)h0 | ((uint)h1 << 16);
        *(uint*)&sAl[idx] = (uint)l0 | ((uint)l1 << 16);
      }
    }
    // ---- stage B ----
    if constexpr (BM == 0) {
      const int r = t >> 1, ks = (t & 1) * 16;
      const size_t g = (size_t)bOff + (size_t)(j0 + r) * ldb + k0 + ks;
      *(short8*)&sBh[r*40+ks]   = *(const short8*)(Bh + g);
      *(short8*)&sBh[r*40+ks+8] = *(const short8*)(Bh + g + 8);
      *(short8*)&sBl[r*40+ks]   = *(const short8*)(Bl + g);
      *(short8*)&sBl[r*40+ks+8] = *(const short8*)(Bl + g + 8);
    } else {  // BM == 1: fp32 [j][k] -> split
      const int r = t >> 1, ks = (t & 1) * 16;
      const float* src = Bf + bOff + (size_t)(j0 + r) * ldb + k0 + ks;
#pragma unroll
      for (int jj = 0; jj < 4; ++jj) {
        float4 f = *(const float4*)(src + 4*jj);
        ushort h0,l0,h1,l1,h2,l2,h3,l3;
        split2(f.x,h0,l0); split2(f.y,h1,l1); split2(f.z,h2,l2); split2(f.w,h3,l3);
        *(ushort4*)&sBh[r*40+ks+4*jj] = make_ushort4(h0,h1,h2,h3);
        *(ushort4*)&sBl[r*40+ks+4*jj] = make_ushort4(l0,l1,l2,l3);
      }
    }
    __syncthreads();
    // ---- compute: 16 tiles x 3 split-MFMAs (skip tiles with all rows < m) ----
    short8 afh[4], afl[4];
#pragma unroll
    for (int mi = 0; mi < 4; ++mi) {
      if (wy*4 + mi >= nsk) {
        const int row = wy*64 + mi*16 + il;
        afh[mi] = *(const short8*)&sAh[row*40 + q*8];
        afl[mi] = *(const short8*)&sAl[row*40 + q*8];
      }
    }
#pragma unroll
    for (int nj = 0; nj < 4; ++nj) {
      const int row = wx*64 + nj*16 + il;
      short8 bfh = *(const short8*)&sBh[row*40 + q*8];
      short8 bfl = *(const short8*)&sBl[row*40 + q*8];
#pragma unroll
      for (int mi = 0; mi < 4; ++mi) {
        if (wy*4 + mi >= nsk) {
          acc[mi][nj] = __builtin_amdgcn_mfma_f32_16x16x32_bf16(afh[mi], bfh, acc[mi][nj], 0, 0, 0);
          acc[mi][nj] = __builtin_amdgcn_mfma_f32_16x16x32_bf16(afh[mi], bfl, acc[mi][nj], 0, 0, 0);
          acc[mi][nj] = __builtin_amdgcn_mfma_f32_16x16x32_bf16(afl[mi], bfh, acc[mi][nj], 0, 0, 0);
        }
      }
    }
  }
  // ---- epilogue: D col = lane&15 (N), row = q*4+r (M) ----
#pragma unroll
  for (int mi = 0; mi < 4; ++mi)
#pragma unroll
    for (int nj = 0; nj < 4; ++nj)
#pragma unroll
      for (int r = 0; r < 4; ++r) {
        const long gi = i0 + wy*64 + mi*16 + q*4 + r;
        const long gj = j0 + wx*64 + nj*16 + il;
        if constexpr (CM == 0) {
          C[cOff + gi*ldc + cColOff + gj] = acc[mi][nj][r];
        } else {
          ushort h, lo; split2(acc[mi][nj][r], h, lo);
          const size_t idx = (size_t)(cOff + gi*ldc + cColOff + gj);
          Ch[idx] = h; Cl[idx] = lo;
        }
      }
}

// ---------------- K3: per-coefficient channel mixing (fp32, in-place-safe) ---
__global__ __launch_bounds__(256) void k_stagec(const float* __restrict__ spec,
                                                const float* __restrict__ w,
                                                float* __restrict__ outb) {
  const int cb = blockIdx.x, l = blockIdx.y;
  if (cb * 16 > l) return;
  __shared__ float s_spec[32 * 257];
  __shared__ float s_w[256 * 33];
  const int t = threadIdx.x;
  const int c = t & 31, og = t >> 5;
  const size_t x0 = 258u * l + cb * 32;
  for (int cc = 0; cc < 32; ++cc)
    s_spec[cc * 257 + t] = spec[(size_t)(cb * 32 + cc) * 32768 + l * 256 + t];
  float acc[8][4] = {{0.f}};
  const int lr = t >> 4;
  const int lq = (t & 15) * 2;
  for (int isub = 0; isub < 4; ++isub) {
    __syncthreads();
    for (int pass = 0; pass < 16; ++pass) {
      const int rho = pass * 16 + lr;
      const int io = (isub * 8 + (rho >> 5)) * 32 + (rho & 31);
      const float2 wv = *(const float2*)&w[(size_t)io * 33024 + x0 + lq];
      s_w[rho * 33 + lq]     = wv.x;
      s_w[rho * 33 + lq + 1] = wv.y;
    }
    __syncthreads();
#pragma unroll
    for (int idp = 0; idp < 4; ++idp) {
      const int i0 = isub * 8 + idp * 2;
      const int r0 = idp * 64;
      float2 sv[8];
#pragma unroll
      for (int b = 0; b < 8; ++b)
        sv[b] = *(const float2*)&s_spec[c * 257 + b * 32 + i0];
      float wv0[4], wv1[4];
#pragma unroll
      for (int od = 0; od < 4; ++od) {
        wv0[od] = s_w[(r0 + og * 4 + od) * 33 + c];
        wv1[od] = s_w[(r0 + 32 + og * 4 + od) * 33 + c];
      }
#pragma unroll
      for (int b = 0; b < 8; ++b)
#pragma unroll
        for (int od = 0; od < 4; ++od)
          acc[b][od] = fmaf(sv[b].x, wv0[od], fmaf(sv[b].y, wv1[od], acc[b][od]));
    }
  }
  __syncthreads();
#pragma unroll
  for (int b = 0; b < 8; ++b)
#pragma unroll
    for (int od = 0; od < 4; ++od)
      s_w[c * 257 + b * 32 + og * 4 + od] = acc[b][od];
  __syncthreads();
  for (int cc = 0; cc < 32; ++cc)
    outb[(size_t)(cb * 32 + cc) * 32768 + l * 256 + t] = s_w[cc * 257 + t];
}

// ---------------- launch ----------------
extern "C" void kernel_launch(void* const* d_in, const int* in_sizes, int n_in,
                              void* d_out, int out_size, void* d_ws, size_t ws_size,
                              hipStream_t stream) {
  const float* x = (const float*)d_in[0];   // (8,32,256,256)
  const float* w = (const float*)d_in[1];   // (32,32,33024)
  float* y = (float*)d_out;                 // (8,32,256,256)
  char* ws = (char*)d_ws;

  // workspace layout (bytes); high-water 134,742,016 <= 168,296,448 available
  ushort* Th   = (ushort*)(ws + 0);          //  256*256 bf16
  ushort* Tl   = (ushort*)(ws + 131072);
  ushort* TiTh = (ushort*)(ws + 262144);     //  [n][mc]
  ushort* TiTl = (ushort*)(ws + 393216);
  ushort* PWh  = (ushort*)(ws + 524288);     //  [m][l][k]  8 MB
  ushort* PWl  = (ushort*)(ws + 8912896);
  ushort* PTh  = (ushort*)(ws + 17301504);   //  [m][k][l]  8 MB
  ushort* PTl  = (ushort*)(ws + 25690112);
  ushort* XHh  = (ushort*)(ws + 34078720);   //  [mc][bc*256+k] bf16-hi (33.5 MB)
  ushort* XHl  = (ushort*)(ws + 67633152);   //  bf16-lo (33.5 MB)
  float* XM    = (float*)(ws + 34078720);    //  [mc][bo*256+k] fp32 (67 MB) — overlays XH after K2/K3
  float* spec  = (float*)(ws + 101187584);   //  [mc][l][bc] fp32 (33.5 MB); K3 in-place -> outb
  float* outb  = spec;

  // K0: tables
  k_tables<<<dim3(129), dim3(256), 0, stream>>>(Th, Tl, TiTh, TiTl, PWh, PWl, PTh, PTl);

  // K1: fwd DFT  XH[mc][row] = sum_n T[mc][n] * x[row][n]; M=256, N=65536, K=256
  mfma_gemm<0,1,1><<<dim3(512, 2, 1), dim3(256), 0, stream>>>(
      Th, Tl, nullptr, nullptr, nullptr, x, nullptr, XHh, XHl,
      256, 256, 65536, 256, 0L, 0, 0L, 0, 0L, 0, 0, 0);

  // K2: fwd Legendre per z=mc: spec[z][l][bc] = sum_k PW[m][l][k]*XH[z][bc][k]
  //     single launch, both bc-halves; skip MFMA tiles fully below l=m.
  mfma_gemm<0,0,0><<<dim3(2, 1, 256), dim3(256), 0, stream>>>(
      PWh, PWl, nullptr, XHh, XHl, nullptr, spec, nullptr, nullptr,
      256, 256, 256, 256, 32768L, 1, 65536L, 0, 32768L, 0, 0, 1);

  // K3: channel mixing (fp32, in-place on spec)
  k_stagec<<<dim3(8, 128), dim3(256), 0, stream>>>(spec, w, outb);

  // K4: inv Legendre per z=mc: XM[z][bo*256+kl] = sum_l outb[z][l][bo]*PT[m][kl][l]
  mfma_gemm<2,0,0><<<dim3(2, 2, 256), dim3(256), 0, stream>>>(
      nullptr, nullptr, outb, PTh, PTl, nullptr, XM, nullptr, nullptr,
      256, 128, 256, 128, 32768L, 0, 32768L, 1, 65536L, 0, 1, 0);

  // K5: inv DFT: y[row][n] = sum_mc XM[mc][row]*TiT[n][mc]
  mfma_gemm<2,0,0><<<dim3(2, 512, 1), dim3(256), 0, stream>>>(
      nullptr, nullptr, XM, TiTh, TiTl, nullptr, y, nullptr, nullptr,
      65536, 256, 256, 256, 0L, 0, 0L, 0, 0L, 0, 0, 0);
}

// Round 4
// 410.246 us; speedup vs baseline: 1.2187x; 1.0109x over previous
//
#include <hip/hip_runtime.h>

// SphericalConvMHF — round 7: global_load_lds staging with XOR chunk-swizzle.
// Pipeline: K0 tables -> K1 fwd-DFT -> K2 fwd-Legendre -> K3 channel-mix
//   -> K4 inv-Legendre -> K5 inv-DFT.  (grids/launches unchanged from R6)
// R7 change (counter/arithmetic-driven): GEMMs run ~210 TF-equiv, ~3x below
// the 2-barrier-structure ceiling; known cause is reg-staged LDS (pitch-40
// forbids global_load_lds). New scheme: linear LDS [128][32 shorts] (64B rows,
// 32 KB total), 16B-chunk XOR swizzle  slot = q ^ ((row>>1)&3):
//   * AM0/BM0 operands staged via __builtin_amdgcn_global_load_lds width=16,
//     swizzle applied to the PER-LANE GLOBAL address (linear LDS dest —
//     rule #21: both-sides-or-neither).
//   * AM2/BM1 conversion paths reg-write LDS at the same swizzled positions.
//   * Compute reads ds_read_b128 at slot q^((il>>1)&3): 2-way bank alias (free).
// Pure data movement — absmax must stay bit-identical.

typedef __attribute__((ext_vector_type(8))) short short8;
typedef __attribute__((ext_vector_type(4))) float f32x4;

__device__ __forceinline__ ushort bf16_rtn(float v) {
  uint u = __float_as_uint(v);
  return (ushort)((u + 0x7FFFu + ((u >> 16) & 1u)) >> 16);
}
__device__ __forceinline__ void split2(float v, ushort& h, ushort& l) {
  h = bf16_rtn(v);
  float hf = __uint_as_float(((uint)h) << 16);
  l = bf16_rtn(v - hf);
}
// async global->LDS, 16 B per lane; dest = wave-uniform base + lane*16 (HW).
__device__ __forceinline__ void gl2lds16(const ushort* g, short* l) {
  __builtin_amdgcn_global_load_lds(
      (const __attribute__((address_space(1))) unsigned int*)g,
      (__attribute__((address_space(3))) unsigned int*)l, 16, 0, 0);
}

// ---------------- K0: table generation (fp64, LDS-hoisted, packed writes) ----
__global__ __launch_bounds__(256) void k_tables(
    ushort* __restrict__ Th, ushort* __restrict__ Tl,
    ushort* __restrict__ TiTh, ushort* __restrict__ TiTl,
    ushort* __restrict__ PWh, ushort* __restrict__ PWl,
    ushort* __restrict__ PTh, ushort* __restrict__ PTl) {
  const double PI = 3.14159265358979323846264338327950288;
  const int t = threadIdx.x;
  const int m = blockIdx.x;
  __shared__ double sCos[256];   // cos table (256-grid for trig block, 255-grid for wq)
  __shared__ double sCoef[128];  // 2/(4kk^2-1)
  __shared__ double sRatio[128]; // (2mm+1)/(2mm)
  __shared__ double sA[128], sB[128];

  if (m == 128) {             // trig tables: T[mc][n] and TiT[n][mc]
    const double scale = 2.0 * PI / 256.0;
    sCos[t] = cos(scale * (double)t);
    __syncthreads();
    const int n = t;
    for (int ch = 0; ch < 8; ++ch) {
      uint th16[16], tl16[16];
#pragma unroll
      for (int j = 0; j < 16; ++j) {
        const int mm = ch * 16 + j;
        const int r = (mm * n) & 255;
        const double c = sCos[r];
        const double s = sCos[(r + 192) & 255];  // sin(2pi r/256) = cos(2pi (r-64)/256)
        const double wm = (mm == 0) ? 1.0 : 2.0;
        ushort h, l;
        split2((float)(scale * c), h, l);  Th[(2*mm)*256+n]=h;   Tl[(2*mm)*256+n]=l;
        split2((float)(-scale * s), h, l); Th[(2*mm+1)*256+n]=h; Tl[(2*mm+1)*256+n]=l;
        ushort h2, l2b, h3, l3;
        split2((float)(wm * c), h2, l2b);
        split2((float)(-wm * s), h3, l3);
        th16[j] = (uint)h2 | ((uint)h3 << 16);
        tl16[j] = (uint)l2b | ((uint)l3 << 16);
      }
      const int base = n * 256 + ch * 32;   // ushort index
#pragma unroll
      for (int q4 = 0; q4 < 4; ++q4) {
        *(uint4*)(TiTh + base + q4 * 8) = make_uint4(th16[4*q4], th16[4*q4+1], th16[4*q4+2], th16[4*q4+3]);
        *(uint4*)(TiTl + base + q4 * 8) = make_uint4(tl16[4*q4], tl16[4*q4+1], tl16[4*q4+2], tl16[4*q4+3]);
      }
    }
    return;
  }

  // ---- cooperative k-independent tables (per block; m is block-uniform) ----
  const double scale255 = 2.0 * PI / 255.0;
  if (t < 255) sCos[t] = cos(scale255 * (double)t);
  if (t >= 1 && t < 128) {
    const double dt = (double)t;
    sCoef[t]  = 2.0 / (4.0 * dt * dt - 1.0);
    sRatio[t] = (2.0 * dt + 1.0) / (2.0 * dt);
    if (t >= m + 2) {
      const double dl = dt, dm = (double)m;
      sA[t] = sqrt((4.0*dl*dl - 1.0) / (dl*dl - dm*dm));
      sB[t] = sqrt(((dl-1.0)*(dl-1.0) - dm*dm) / (4.0*(dl-1.0)*(dl-1.0) - 1.0));
    }
  }
  __syncthreads();

  const int k = t;  // latitude index
  const double tj = PI * (double)k / 255.0;
  double ssum = 0.0;
  {
    int r = 0;
    for (int kk = 1; kk <= 127; ++kk) {
      r += k; if (r >= 255) r -= 255;
      ssum += sCoef[kk] * sCos[r];
    }
  }
  const double cj = (k == 0 || k == 255) ? 1.0 : 2.0;
  const double wq = cj / 255.0 * (1.0 - ssum);
  const double ct = cos(tj), st = sin(tj);
  double prod = 1.0, stp = 1.0;
  for (int mm = 1; mm <= m; ++mm) { prod *= sRatio[mm]; stp *= -st; }
  const double pmm = (1.0 / sqrt(4.0 * PI)) * sqrt(prod) * stp;
  const double sq2m3 = sqrt(2.0 * (double)m + 3.0);

  const size_t pwB = (size_t)m * 32768;                   // [l][k]
  const size_t ptB = (size_t)m * 32768 + (size_t)k * 128; // [k][l]
  double plm1 = 0.0, plm2 = 0.0;
  for (int lc0 = 0; lc0 < 128; lc0 += 16) {
    uint hq[8], lq[8];
#pragma unroll
    for (int j = 0; j < 16; ++j) {
      const int l = lc0 + j;
      double val;
      if (l < m)           val = 0.0;
      else if (l == m)     val = pmm;
      else if (l == m + 1) val = sq2m3 * ct * pmm;
      else                 val = sA[l] * (ct * plm1 - sB[l] * plm2);
      plm2 = plm1; plm1 = val;
      ushort h, lo; split2((float)val, h, lo);
      if ((j & 1) == 0) { hq[j>>1] = (uint)h; lq[j>>1] = (uint)lo; }
      else              { hq[j>>1] |= ((uint)h) << 16; lq[j>>1] |= ((uint)lo) << 16; }
      ushort hw, lw; split2((float)(val * wq), hw, lw);
      PWh[pwB + (size_t)l * 256 + k] = hw;   // coalesced across threads per l
      PWl[pwB + (size_t)l * 256 + k] = lw;
    }
    *(uint4*)(PTh + ptB + lc0)     = make_uint4(hq[0], hq[1], hq[2], hq[3]);
    *(uint4*)(PTh + ptB + lc0 + 8) = make_uint4(hq[4], hq[5], hq[6], hq[7]);
    *(uint4*)(PTl + ptB + lc0)     = make_uint4(lq[0], lq[1], lq[2], lq[3]);
    *(uint4*)(PTl + ptB + lc0 + 8) = make_uint4(lq[4], lq[5], lq[6], lq[7]);
  }
}

// ---------------- split-bf16 MFMA GEMM ----------------
// C[i][j] = sum_k A[i][k]*B[j][k]. Block 128x128, 4 waves (64x64 each), BK=32.
// AM: 0 = A pre-split bf16 [i][k] via global_load_lds; 2 = fp32 [k][i] cvt.
// BM: 0 = B pre-split bf16 [j][k] via global_load_lds; 1 = fp32 [j][k] cvt.
// CM: 0 = fp32 C; 1 = split-bf16 pair (Ch/Cl).
// LDS: linear [128][32 shorts]; 16B-chunk swizzle slot = q ^ ((row>>1)&3).
template<int AM, int BM, int CM>
__global__ __launch_bounds__(256) void mfma_gemm(
    const ushort* __restrict__ Ah, const ushort* __restrict__ Al, const float* __restrict__ Af,
    const ushort* __restrict__ Bh, const ushort* __restrict__ Bl, const float* __restrict__ Bf,
    float* __restrict__ C, ushort* __restrict__ Ch, ushort* __restrict__ Cl,
    int lda, int ldb, int ldc, int K,
    long aZ, int aShift, long bZ, int bShift, long cZ, int cColOff,
    int kFromZ, int mSkipFromZ)
{
  __shared__ __align__(16) short sAh[128*32];
  __shared__ __align__(16) short sAl[128*32];
  __shared__ __align__(16) short sBh[128*32];
  __shared__ __align__(16) short sBl[128*32];
  const int z = blockIdx.z;
  const long aOff = ((long)(z >> aShift)) * aZ;
  const long bOff = ((long)(z >> bShift)) * bZ;
  const long cOff = (long)z * cZ;
  const int i0 = blockIdx.y * 128;
  const int j0 = blockIdx.x * 128;
  const int t = threadIdx.x;
  const int lane = t & 63, w = t >> 6;
  const int wy = w >> 1, wx = w & 1;
  const int il = lane & 15, q = lane >> 4;
  const int kstart = kFromZ ? ((z >> 1) & ~31) : 0;
  const int nsk = mSkipFromZ ? ((z >> 1) >> 4) : 0;   // fully-zero 16-row tiles
  // gload staging geometry: wave w stages rows [w*32, w*32+32) of each buffer.
  const int grow0 = w * 32 + (lane >> 2);            // rows for inst 0 (inst1: +16)
  const int gchunk0 = (lane & 3) ^ ((lane >> 3) & 3);// global 16B-chunk, inst-invariant
  // read-side swizzled slot (row base bits contribute 0: all bases mult of 8)
  const int cq = q ^ ((il >> 1) & 3);

  f32x4 acc[4][4];
#pragma unroll
  for (int a = 0; a < 4; ++a)
#pragma unroll
    for (int b = 0; b < 4; ++b) acc[a][b] = (f32x4){0.f, 0.f, 0.f, 0.f};

  for (int k0 = kstart; k0 < K; k0 += 32) {
    __syncthreads();
    // ---- stage A ----
    if constexpr (AM == 0) {
#pragma unroll
      for (int inst = 0; inst < 2; ++inst) {
        const int r = grow0 + inst * 16;
        const size_t g = (size_t)aOff + (size_t)(i0 + r) * lda + k0 + gchunk0 * 8;
        short* dA = &sAh[(w * 32 + inst * 16) * 32];
        short* dAl = &sAl[(w * 32 + inst * 16) * 32];
        gl2lds16(Ah + g, dA);
        gl2lds16(Al + g, dAl);
      }
    } else {  // AM == 2: fp32 [k][i] -> transpose + split, swizzled reg-write
      const int kk0 = 8*w + 2*q;               // even, 0..30
      const int cbase = kk0 >> 3, koff = kk0 & 7;
      const float* s0 = Af + aOff + (size_t)(k0 + kk0) * lda + i0 + il;
      const float* s1 = s0 + lda;
#pragma unroll
      for (int c = 0; c < 8; ++c) {
        float v0 = s0[c*16], v1 = s1[c*16];
        ushort h0,l0,h1,l1; split2(v0,h0,l0); split2(v1,h1,l1);
        const int row = il + 16*c;
        const int idx = row*32 + ((cbase ^ ((row>>1)&3)) << 3) + koff;
        *(uint*)&sAh[idx] = (uint)h0 | ((uint)h1 << 16);
        *(uint*)&sAl[idx] = (uint)l0 | ((uint)l1 << 16);
      }
    }
    // ---- stage B ----
    if constexpr (BM == 0) {
#pragma unroll
      for (int inst = 0; inst < 2; ++inst) {
        const int r = grow0 + inst * 16;
        const size_t g = (size_t)bOff + (size_t)(j0 + r) * ldb + k0 + gchunk0 * 8;
        short* dB = &sBh[(w * 32 + inst * 16) * 32];
        short* dBl = &sBl[(w * 32 + inst * 16) * 32];
        gl2lds16(Bh + g, dB);
        gl2lds16(Bl + g, dBl);
      }
    } else {  // BM == 1: fp32 [j][k] -> split, swizzled reg-write
      const int rr = t >> 1, ks = (t & 1) * 16;
      const int rsw = (rr >> 1) & 3;
      const float* src = Bf + bOff + (size_t)(j0 + rr) * ldb + k0 + ks;
#pragma unroll
      for (int jj = 0; jj < 4; ++jj) {
        float4 f = *(const float4*)(src + 4*jj);
        ushort h0,l0,h1,l1,h2,l2,h3,l3;
        split2(f.x,h0,l0); split2(f.y,h1,l1); split2(f.z,h2,l2); split2(f.w,h3,l3);
        const int pos = ks + 4*jj;
        const int idx = rr*32 + ((((pos >> 3) ^ rsw)) << 3) + (pos & 7);
        *(ushort4*)&sBh[idx] = make_ushort4(h0,h1,h2,h3);
        *(ushort4*)&sBl[idx] = make_ushort4(l0,l1,l2,l3);
      }
    }
    __syncthreads();
    // ---- compute: 16 tiles x 3 split-MFMAs (skip tiles with all rows < m) ----
    short8 afh[4], afl[4];
#pragma unroll
    for (int mi = 0; mi < 4; ++mi) {
      if (wy*4 + mi >= nsk) {
        const int row = wy*64 + mi*16 + il;
        afh[mi] = *(const short8*)&sAh[row*32 + cq*8];
        afl[mi] = *(const short8*)&sAl[row*32 + cq*8];
      }
    }
#pragma unroll
    for (int nj = 0; nj < 4; ++nj) {
      const int row = wx*64 + nj*16 + il;
      short8 bfh = *(const short8*)&sBh[row*32 + cq*8];
      short8 bfl = *(const short8*)&sBl[row*32 + cq*8];
#pragma unroll
      for (int mi = 0; mi < 4; ++mi) {
        if (wy*4 + mi >= nsk) {
          acc[mi][nj] = __builtin_amdgcn_mfma_f32_16x16x32_bf16(afh[mi], bfh, acc[mi][nj], 0, 0, 0);
          acc[mi][nj] = __builtin_amdgcn_mfma_f32_16x16x32_bf16(afh[mi], bfl, acc[mi][nj], 0, 0, 0);
          acc[mi][nj] = __builtin_amdgcn_mfma_f32_16x16x32_bf16(afl[mi], bfh, acc[mi][nj], 0, 0, 0);
        }
      }
    }
  }
  // ---- epilogue: D col = lane&15 (N), row = q*4+r (M) ----
#pragma unroll
  for (int mi = 0; mi < 4; ++mi)
#pragma unroll
    for (int nj = 0; nj < 4; ++nj)
#pragma unroll
      for (int r = 0; r < 4; ++r) {
        const long gi = i0 + wy*64 + mi*16 + q*4 + r;
        const long gj = j0 + wx*64 + nj*16 + il;
        if constexpr (CM == 0) {
          C[cOff + gi*ldc + cColOff + gj] = acc[mi][nj][r];
        } else {
          ushort h, lo; split2(acc[mi][nj][r], h, lo);
          const size_t idx = (size_t)(cOff + gi*ldc + cColOff + gj);
          Ch[idx] = h; Cl[idx] = lo;
        }
      }
}

// ---------------- K3: per-coefficient channel mixing (fp32, in-place-safe) ---
__global__ __launch_bounds__(256) void k_stagec(const float* __restrict__ spec,
                                                const float* __restrict__ w,
                                                float* __restrict__ outb) {
  const int cb = blockIdx.x, l = blockIdx.y;
  if (cb * 16 > l) return;
  __shared__ float s_spec[32 * 257];
  __shared__ float s_w[256 * 33];
  const int t = threadIdx.x;
  const int c = t & 31, og = t >> 5;
  const size_t x0 = 258u * l + cb * 32;
  for (int cc = 0; cc < 32; ++cc)
    s_spec[cc * 257 + t] = spec[(size_t)(cb * 32 + cc) * 32768 + l * 256 + t];
  float acc[8][4] = {{0.f}};
  const int lr = t >> 4;
  const int lq = (t & 15) * 2;
  for (int isub = 0; isub < 4; ++isub) {
    __syncthreads();
    for (int pass = 0; pass < 16; ++pass) {
      const int rho = pass * 16 + lr;
      const int io = (isub * 8 + (rho >> 5)) * 32 + (rho & 31);
      const float2 wv = *(const float2*)&w[(size_t)io * 33024 + x0 + lq];
      s_w[rho * 33 + lq]     = wv.x;
      s_w[rho * 33 + lq + 1] = wv.y;
    }
    __syncthreads();
#pragma unroll
    for (int idp = 0; idp < 4; ++idp) {
      const int i0 = isub * 8 + idp * 2;
      const int r0 = idp * 64;
      float2 sv[8];
#pragma unroll
      for (int b = 0; b < 8; ++b)
        sv[b] = *(const float2*)&s_spec[c * 257 + b * 32 + i0];
      float wv0[4], wv1[4];
#pragma unroll
      for (int od = 0; od < 4; ++od) {
        wv0[od] = s_w[(r0 + og * 4 + od) * 33 + c];
        wv1[od] = s_w[(r0 + 32 + og * 4 + od) * 33 + c];
      }
#pragma unroll
      for (int b = 0; b < 8; ++b)
#pragma unroll
        for (int od = 0; od < 4; ++od)
          acc[b][od] = fmaf(sv[b].x, wv0[od], fmaf(sv[b].y, wv1[od], acc[b][od]));
    }
  }
  __syncthreads();
#pragma unroll
  for (int b = 0; b < 8; ++b)
#pragma unroll
    for (int od = 0; od < 4; ++od)
      s_w[c * 257 + b * 32 + og * 4 + od] = acc[b][od];
  __syncthreads();
  for (int cc = 0; cc < 32; ++cc)
    outb[(size_t)(cb * 32 + cc) * 32768 + l * 256 + t] = s_w[cc * 257 + t];
}

// ---------------- launch ----------------
extern "C" void kernel_launch(void* const* d_in, const int* in_sizes, int n_in,
                              void* d_out, int out_size, void* d_ws, size_t ws_size,
                              hipStream_t stream) {
  const float* x = (const float*)d_in[0];   // (8,32,256,256)
  const float* w = (const float*)d_in[1];   // (32,32,33024)
  float* y = (float*)d_out;                 // (8,32,256,256)
  char* ws = (char*)d_ws;

  // workspace layout (bytes); high-water 134,742,016 <= 168,296,448 available
  ushort* Th   = (ushort*)(ws + 0);          //  256*256 bf16
  ushort* Tl   = (ushort*)(ws + 131072);
  ushort* TiTh = (ushort*)(ws + 262144);     //  [n][mc]
  ushort* TiTl = (ushort*)(ws + 393216);
  ushort* PWh  = (ushort*)(ws + 524288);     //  [m][l][k]  8 MB
  ushort* PWl  = (ushort*)(ws + 8912896);
  ushort* PTh  = (ushort*)(ws + 17301504);   //  [m][k][l]  8 MB
  ushort* PTl  = (ushort*)(ws + 25690112);
  ushort* XHh  = (ushort*)(ws + 34078720);   //  [mc][bc*256+k] bf16-hi (33.5 MB)
  ushort* XHl  = (ushort*)(ws + 67633152);   //  bf16-lo (33.5 MB)
  float* XM    = (float*)(ws + 34078720);    //  [mc][bo*256+k] fp32 (67 MB) — overlays XH after K2/K3
  float* spec  = (float*)(ws + 101187584);   //  [mc][l][bc] fp32 (33.5 MB); K3 in-place -> outb
  float* outb  = spec;

  // K0: tables
  k_tables<<<dim3(129), dim3(256), 0, stream>>>(Th, Tl, TiTh, TiTl, PWh, PWl, PTh, PTl);

  // K1: fwd DFT  XH[mc][row] = sum_n T[mc][n] * x[row][n]; M=256, N=65536, K=256
  mfma_gemm<0,1,1><<<dim3(512, 2, 1), dim3(256), 0, stream>>>(
      Th, Tl, nullptr, nullptr, nullptr, x, nullptr, XHh, XHl,
      256, 256, 65536, 256, 0L, 0, 0L, 0, 0L, 0, 0, 0);

  // K2: fwd Legendre per z=mc: spec[z][l][bc] = sum_k PW[m][l][k]*XH[z][bc][k]
  mfma_gemm<0,0,0><<<dim3(2, 1, 256), dim3(256), 0, stream>>>(
      PWh, PWl, nullptr, XHh, XHl, nullptr, spec, nullptr, nullptr,
      256, 256, 256, 256, 32768L, 1, 65536L, 0, 32768L, 0, 0, 1);

  // K3: channel mixing (fp32, in-place on spec)
  k_stagec<<<dim3(8, 128), dim3(256), 0, stream>>>(spec, w, outb);

  // K4: inv Legendre per z=mc: XM[z][bo*256+kl] = sum_l outb[z][l][bo]*PT[m][kl][l]
  mfma_gemm<2,0,0><<<dim3(2, 2, 256), dim3(256), 0, stream>>>(
      nullptr, nullptr, outb, PTh, PTl, nullptr, XM, nullptr, nullptr,
      256, 128, 256, 128, 32768L, 0, 32768L, 1, 65536L, 0, 1, 0);

  // K5: inv DFT: y[row][n] = sum_mc XM[mc][row]*TiT[n][mc]
  mfma_gemm<2,0,0><<<dim3(2, 512, 1), dim3(256), 0, stream>>>(
      nullptr, nullptr, XM, TiTh, TiTl, nullptr, y, nullptr, nullptr,
      65536, 256, 256, 256, 0L, 0, 0L, 0, 0L, 0, 0, 0);
}